// Round 14
// baseline (282.902 us; speedup 1.0000x reference)
//
#include <hip/hip_runtime.h>
#include <hip/hip_bf16.h>
#include <hip/hip_fp16.h>

#define N_NODES 50000
#define N_EDGES 800000
#define NTILES 3125        // N_NODES / 16
#define W_TOTAL 57344      // packed f16 weight elements (W1 slot unused)
#define WB2 192            // pack blocks (W2..A4b = 49152 elems)
#define CLS_UNITS 1024     // classed edge-walk blocks
#define CLS_STRIDE (128 * 256)
#define CLS_RANGE 6250     // dst nodes per class (8 * 6250 = 50000)
#define TB 782             // layer1/dense MFMA blocks (4 waves each)
#define ROWCAP 64          // padded-CSR slots per node (deg mean 16, 12-sigma safe)
#define ISQ_NB 196         // isq kernel blocks

typedef __attribute__((ext_vector_type(8))) _Float16 h16x8;   // MFMA f16 A/B frag
typedef __attribute__((ext_vector_type(2))) _Float16 h16x2;
typedef __attribute__((ext_vector_type(4))) float f32x4;      // MFMA C/D frag

__device__ inline float2 h2f2(unsigned int u) {   // packed half2 -> float2
    union { unsigned int u32; h16x2 h; } cv;
    cv.u32 = u;
    return make_float2((float)cv.h.x, (float)cv.h.y);
}

// ---------------------------------------------------------------------------
// PASS 1 (one launch, three independent block roles):
//  [0, CLS_UNITS)      : padded-CSR scatter+count (atomicAdd is count AND cursor).
//  [CLS_UNITS, +TB)    : layer1 MFMA f16, W1 converted fp32->fp16 inline;
//                        writes UNSCALED h (fp16) to Ht.
//  [CLS_UNITS+TB, end) : fp16-pack W2..A4b into wp[8192..].
__global__ __launch_bounds__(256) void pass1_kernel(
    const float* __restrict__ x, const int* __restrict__ src, const int* __restrict__ dst,
    const float* __restrict__ W1, const float* __restrict__ b1,
    const float* W2, const float* A2a, const float* A2b,
    const float* W3, const float* A3a, const float* A3b,
    const float* W4, const float* A4a, const float* A4b,
    int* __restrict__ cnt, unsigned short* __restrict__ srcAp,
    _Float16* __restrict__ wp, _Float16* __restrict__ Ht) {
    int tid = threadIdx.x;

    if (blockIdx.x < CLS_UNITS) {                 // ---- scatter + count ----
        int cls = blockIdx.x & 7;
        int k = blockIdx.x >> 3;
        int lo = cls * CLS_RANGE, hi = lo + CLS_RANGE;
        for (int e = k * 256 + tid; e < N_EDGES; e += CLS_STRIDE) {
            int d = dst[e];
            if (d >= lo && d < hi) {
                int pos = atomicAdd(&cnt[d], 1);
                if (pos < ROWCAP) srcAp[(size_t)d * ROWCAP + pos] = (unsigned short)src[e];
            }
        }
        return;
    }
    if (blockIdx.x >= CLS_UNITS + TB) {           // ---- pack W2..A4b (fp16) ----
        int i = 8192 + (blockIdx.x - CLS_UNITS - TB) * 256 + tid;
        if (i >= W_TOTAL) return;
        float v;
        if (i < 16384)      v = W2[i - 8192];
        else if (i < 20480) v = A2a[i - 16384];
        else if (i < 24576) v = A2b[i - 20480];
        else if (i < 32768) v = W3[i - 24576];
        else if (i < 36864) v = A3a[i - 32768];
        else if (i < 40960) v = A3b[i - 36864];
        else if (i < 49152) v = W4[i - 40960];
        else if (i < 53248) v = A4a[i - 49152];
        else                v = A4b[i - 53248];
        wp[i] = (_Float16)v;
        return;
    }

    // ---- layer1: h = relu(x @ W1^T + b1) -> Ht (fp16, unscaled) ----
    int wave = ((blockIdx.x - CLS_UNITS) * 256 + tid) >> 6;
    if (wave >= NTILES) return;
    int lane = tid & 63;
    int r16 = lane & 15, quad = lane >> 4;
    int base = wave * 16;

    h16x8 a[4];
    const float* xr = x + (size_t)(base + r16) * 128 + quad * 8;
#pragma unroll
    for (int kb = 0; kb < 4; kb++) {
        float4 f0 = *(const float4*)(xr + kb * 32);
        float4 f1 = *(const float4*)(xr + kb * 32 + 4);
        h16x8 v;
        v[0] = (_Float16)f0.x; v[1] = (_Float16)f0.y;
        v[2] = (_Float16)f0.z; v[3] = (_Float16)f0.w;
        v[4] = (_Float16)f1.x; v[5] = (_Float16)f1.y;
        v[6] = (_Float16)f1.z; v[7] = (_Float16)f1.w;
        a[kb] = v;
    }

#pragma unroll
    for (int jt = 0; jt < 4; jt++) {
        f32x4 acc = {0.f, 0.f, 0.f, 0.f};
        const float* wr = W1 + (size_t)(jt * 16 + r16) * 128 + quad * 8;
#pragma unroll
        for (int kb = 0; kb < 4; kb++) {
            float4 g0 = *(const float4*)(wr + kb * 32);
            float4 g1 = *(const float4*)(wr + kb * 32 + 4);
            h16x8 b;
            b[0] = (_Float16)g0.x; b[1] = (_Float16)g0.y;
            b[2] = (_Float16)g0.z; b[3] = (_Float16)g0.w;
            b[4] = (_Float16)g1.x; b[5] = (_Float16)g1.y;
            b[6] = (_Float16)g1.z; b[7] = (_Float16)g1.w;
            acc = __builtin_amdgcn_mfma_f32_16x16x32_f16(a[kb], b, acc, 0, 0, 0);
        }
        int col = jt * 16 + r16;
        float bias = b1[col];
#pragma unroll
        for (int r = 0; r < 4; r++) {
            int row = base + quad * 4 + r;
            float v = fmaxf(acc[r] + bias, 0.f);
            Ht[(size_t)row * 64 + col] = (_Float16)v;
        }
    }
}

// ---------------------------------------------------------------------------
// isq/sdeg from cnt (tiny).
__global__ __launch_bounds__(256) void isq_kernel(const int* __restrict__ cnt,
                                                  float* __restrict__ isq,
                                                  _Float16* __restrict__ sdeg) {
    int i = blockIdx.x * 256 + threadIdx.x;
    if (i >= N_NODES) return;
    float dv = fmaxf((float)cnt[i], 1.0f);
    isq[i] = rsqrtf(dv);
    sdeg[i] = (_Float16)sqrtf(dv);
}

// ---------------------------------------------------------------------------
// FUSED conv + dense, one block = 64 rows (4 MFMA tiles, wave-independent).
// conv: padded CSR (row base d*64); 8 feat-lanes x uint4 = 16B gather, one
//   instr serves 8 edges; unroll 8 -> 8 independent gathers in flight.
//   perEdgeScale: layer-2 gathers raw Ht and scales by isq[s] per edge;
//   layers 3-4 gather pre-scaled hs (w = 1).
// dense: A-frags = raw f16 rows x (useSdeg ? sdeg : 1) via packed f16 mul.
__global__ __launch_bounds__(256) void conv_dense_k(const _Float16* __restrict__ hs,
                                                    const int* __restrict__ cnt,
                                                    const unsigned short* __restrict__ srcAp,
                                                    const float* __restrict__ isq,
                                                    const _Float16* __restrict__ sdeg,
                                                    const _Float16* __restrict__ wp,
                                                    const _Float16* __restrict__ aap,
                                                    const _Float16* __restrict__ abp,
                                                    _Float16* __restrict__ outs,
                                                    float* __restrict__ outf,
                                                    int perEdgeScale,
                                                    int finalLayer) {
    __shared__ _Float16 clds[64][64];   // conv result (f16), 8 KB
    int tid = threadIdx.x;
    int wv = tid >> 6;
    int lane = tid & 63;
    int t = blockIdx.x * 4 + wv;
    if (t >= NTILES) return;
    int base = t * 16;   // N_NODES % 16 == 0: all rows valid

    // ---- conv phase (no barrier: wave reads only its own clds quarter) ----
    {
        int e8 = lane >> 3, fl = lane & 7;
        const unsigned int* hsp = (const unsigned int*)hs;  // row = 32 uints
#pragma unroll
        for (int g = 0; g < 2; g++) {
            int lrow = g * 8 + e8;
            int row = base + lrow;
            int b = row * ROWCAP;
            int cntv = cnt[row];
            int cv = min(cntv, ROWCAP);
            float acc[8];
#pragma unroll
            for (int k = 0; k < 8; k++) acc[k] = 0.f;
            for (int i = 0; i < cv; i += 8) {
#pragma unroll
                for (int u = 0; u < 8; u++) {
                    int j = i + u;
                    bool ok = j < cv;
                    int s = srcAp[b + j];     // in-bounds slots; poison=0xAAAA<50000 safe
                    uint4 raw = *(const uint4*)(hsp + (size_t)s * 32 + fl * 4);
                    float w;
                    if (perEdgeScale) w = ok ? isq[s] : 0.f;
                    else              w = ok ? 1.f : 0.f;
                    float2 f0 = h2f2(raw.x), f1 = h2f2(raw.y);
                    float2 f2 = h2f2(raw.z), f3 = h2f2(raw.w);
                    acc[0] = fmaf(f0.x, w, acc[0]); acc[1] = fmaf(f0.y, w, acc[1]);
                    acc[2] = fmaf(f1.x, w, acc[2]); acc[3] = fmaf(f1.y, w, acc[3]);
                    acc[4] = fmaf(f2.x, w, acc[4]); acc[5] = fmaf(f2.y, w, acc[5]);
                    acc[6] = fmaf(f3.x, w, acc[6]); acc[7] = fmaf(f3.y, w, acc[7]);
                }
            }
            float sc = rsqrtf(fmaxf((float)cntv, 1.0f));   // isq[row] inline
            h16x8 o;
#pragma unroll
            for (int k = 0; k < 8; k++) o[k] = (_Float16)(acc[k] * sc);
            *(h16x8*)(&clds[lrow + wv * 16][fl * 8]) = o;
        }
    }

    // ---- dense phase ----
    int r16 = lane & 15, quad = lane >> 4;
    _Float16 rs = finalLayer || !perEdgeScale ? sdeg[base + r16] : (_Float16)1.0f;
    // L2 (perEdgeScale): hs holds raw h -> rs=1. L3/4: hs pre-scaled -> rs=sdeg.
    if (perEdgeScale) rs = (_Float16)1.0f;
    const _Float16* hr = hs + (size_t)(base + r16) * 64 + quad * 8;
    h16x8 ha0 = *(const h16x8*)(hr) * rs;        // packed f16 mul (splat)
    h16x8 ha1 = *(const h16x8*)(hr + 32) * rs;
    h16x8 ca0 = *(const h16x8*)(&clds[wv * 16 + r16][quad * 8]);
    h16x8 ca1 = *(const h16x8*)(&clds[wv * 16 + r16][32 + quad * 8]);

    float isq4[4];
    if (!finalLayer) {
#pragma unroll
        for (int r = 0; r < 4; r++) isq4[r] = isq[base + quad * 4 + r];
    }

#pragma unroll
    for (int jt = 0; jt < 4; jt++) {
        const _Float16* wr = wp + (size_t)(jt * 16 + r16) * 128 + quad * 8;
        const _Float16* ar = aap + (size_t)(jt * 16 + r16) * 64 + quad * 8;
        const _Float16* br = abp + (size_t)(jt * 16 + r16) * 64 + quad * 8;
        f32x4 P = {0.f, 0.f, 0.f, 0.f};
        f32x4 Q = {0.f, 0.f, 0.f, 0.f};
        f32x4 R = {0.f, 0.f, 0.f, 0.f};
        P = __builtin_amdgcn_mfma_f32_16x16x32_f16(ha0, *(const h16x8*)(wr), P, 0, 0, 0);
        P = __builtin_amdgcn_mfma_f32_16x16x32_f16(ha1, *(const h16x8*)(wr + 32), P, 0, 0, 0);
        P = __builtin_amdgcn_mfma_f32_16x16x32_f16(ca0, *(const h16x8*)(wr + 64), P, 0, 0, 0);
        P = __builtin_amdgcn_mfma_f32_16x16x32_f16(ca1, *(const h16x8*)(wr + 96), P, 0, 0, 0);
        Q = __builtin_amdgcn_mfma_f32_16x16x32_f16(ha0, *(const h16x8*)(ar), Q, 0, 0, 0);
        Q = __builtin_amdgcn_mfma_f32_16x16x32_f16(ha1, *(const h16x8*)(ar + 32), Q, 0, 0, 0);
        R = __builtin_amdgcn_mfma_f32_16x16x32_f16(ha0, *(const h16x8*)(br), R, 0, 0, 0);
        R = __builtin_amdgcn_mfma_f32_16x16x32_f16(ha1, *(const h16x8*)(br + 32), R, 0, 0, 0);
        int col = jt * 16 + r16;
#pragma unroll
        for (int r = 0; r < 4; r++) {
            int row = base + quad * 4 + r;
            float v = fmaxf(P[r] + Q[r] * R[r], 0.f);
            if (finalLayer) outf[(size_t)row * 64 + col] = v;
            else            outs[(size_t)row * 64 + col] = (_Float16)(v * isq4[r]);
        }
    }
}

// ---------------------------------------------------------------------------
extern "C" void kernel_launch(void* const* d_in, const int* in_sizes, int n_in,
                              void* d_out, int out_size, void* d_ws, size_t ws_size,
                              hipStream_t stream) {
    const float* x = (const float*)d_in[0];
    const int* edges = (const int*)d_in[1];
    const float* W1 = (const float*)d_in[2];
    const float* b1 = (const float*)d_in[3];
    const float* W2 = (const float*)d_in[4];
    const float* A2a = (const float*)d_in[5];
    const float* A2b = (const float*)d_in[6];
    const float* W3 = (const float*)d_in[7];
    const float* A3a = (const float*)d_in[8];
    const float* A3b = (const float*)d_in[9];
    const float* W4 = (const float*)d_in[10];
    const float* A4a = (const float*)d_in[11];
    const float* A4b = (const float*)d_in[12];
    float* out = (float*)d_out;

    const int* src = edges;
    const int* dst = edges + N_EDGES;

    char* p = (char*)d_ws;
    auto alloc = [&](size_t bytes) {
        char* r = p;
        p += (bytes + 255) & ~(size_t)255;
        return r;
    };
    int* cnt              = (int*)alloc(N_NODES * 4);
    float* isq            = (float*)alloc(N_NODES * 4);
    _Float16* sdeg        = (_Float16*)alloc(N_NODES * 2);
    unsigned short* srcAp = (unsigned short*)alloc((size_t)N_NODES * ROWCAP * 2);
    _Float16* wpAll       = (_Float16*)alloc(W_TOTAL * 2);
    _Float16* Ht          = (_Float16*)alloc((size_t)N_NODES * 64 * 2);  // raw h1
    _Float16* Bs          = (_Float16*)alloc((size_t)N_NODES * 64 * 2);  // pre-scaled
    _Float16* As          = (_Float16*)alloc((size_t)N_NODES * 64 * 2);  // pre-scaled

    const _Float16* W2p  = wpAll + 8192;
    const _Float16* A2ap = wpAll + 16384;
    const _Float16* A2bp = wpAll + 20480;
    const _Float16* W3p  = wpAll + 24576;
    const _Float16* A3ap = wpAll + 32768;
    const _Float16* A3bp = wpAll + 36864;
    const _Float16* W4p  = wpAll + 40960;
    const _Float16* A4ap = wpAll + 49152;
    const _Float16* A4bp = wpAll + 53248;

    // ---- pass 1: scatter+count (padded CSR) || layer1 (f16) || weight pack ----
    hipMemsetAsync(cnt, 0, N_NODES * 4, stream);
    pass1_kernel<<<CLS_UNITS + TB + WB2, 256, 0, stream>>>(
        x, src, dst, W1, b1, W2, A2a, A2b, W3, A3a, A3b, W4, A4a, A4b,
        cnt, srcAp, wpAll, Ht);

    // ---- isq/sdeg (tiny) ----
    isq_kernel<<<ISQ_NB, 256, 0, stream>>>(cnt, isq, sdeg);

    // ---- layer 2: Ht (raw, per-edge isq scale) -> Bs (pre-scaled) ----
    conv_dense_k<<<TB, 256, 0, stream>>>(Ht, cnt, srcAp, isq, sdeg,
                                         W2p, A2ap, A2bp, Bs, nullptr, 1, 0);
    // ---- layer 3: Bs -> As ----
    conv_dense_k<<<TB, 256, 0, stream>>>(Bs, cnt, srcAp, isq, sdeg,
                                         W3p, A3ap, A3bp, As, nullptr, 0, 0);
    // ---- layer 4: As -> out (fp32) ----
    conv_dense_k<<<TB, 256, 0, stream>>>(As, cnt, srcAp, isq, sdeg,
                                         W4p, A4ap, A4bp, nullptr, out, 0, 1);
}

// Round 15
// 228.082 us; speedup vs baseline: 1.2404x; 1.2404x over previous
//
#include <hip/hip_runtime.h>
#include <hip/hip_bf16.h>
#include <hip/hip_fp16.h>

#define N_NODES 50000
#define N_EDGES 800000
#define NTILES 3125        // N_NODES / 16
#define W_TOTAL 57344      // packed bf16 weight elements (W1 slot unused)
#define WB2 192            // pack blocks (W2..A4b = 49152 elems)
#define CLS_UNITS 1024     // classed edge-walk blocks
#define CLS_STRIDE (128 * 256)
#define CLS_RANGE 6250     // dst nodes per class (8 * 6250 = 50000)
#define TB 782             // layer1/dense MFMA blocks (4 waves each)
#define ROWCAP 64          // padded-CSR slots per node (deg mean 16, 12-sigma safe)

typedef __attribute__((ext_vector_type(8))) short bf16x8;          // MFMA A/B frag
typedef __attribute__((ext_vector_type(4))) float f32x4;           // MFMA C/D frag
typedef __attribute__((ext_vector_type(8))) unsigned short u16x8;  // 16B load/store

__device__ inline unsigned short f2bf(float f) {  // round-to-nearest-even
    unsigned int x = __float_as_uint(f);
    unsigned int r = (x + 0x7FFF + ((x >> 16) & 1)) >> 16;
    return (unsigned short)r;
}
__device__ inline float2 h2f2(unsigned int u) {   // packed half2 -> float2
    __half2 h = *(__half2*)&u;
    return make_float2(__low2float(h), __high2float(h));
}
__device__ inline unsigned int f22h2(float a, float b) {  // 2 floats -> packed half2
    __half2 h = __floats2half2_rn(a, b);
    return *(unsigned int*)&h;
}

// ---------------------------------------------------------------------------
// PASS 1 (one launch, three independent block roles):
//  [0, CLS_UNITS)      : padded-CSR scatter+count. atomicAdd(cnt[d]) returns the
//                        slot AND accumulates the degree -- no prefix scan needed.
//  [CLS_UNITS, +TB)    : layer1 MFMA, W1 converted fp32->bf16 inline; writes
//                        UNSCALED h (fp16) to Ht.
//  [CLS_UNITS+TB, end) : bf16-pack W2..A4b into wpAll[8192..].
__global__ __launch_bounds__(256) void pass1_kernel(
    const float* __restrict__ x, const int* __restrict__ src, const int* __restrict__ dst,
    const float* __restrict__ W1, const float* __restrict__ b1,
    const float* W2, const float* A2a, const float* A2b,
    const float* W3, const float* A3a, const float* A3b,
    const float* W4, const float* A4a, const float* A4b,
    int* __restrict__ cnt, unsigned short* __restrict__ srcAp,
    unsigned short* __restrict__ wp, __half* __restrict__ Ht) {
    int tid = threadIdx.x;

    if (blockIdx.x < CLS_UNITS) {                 // ---- scatter + count ----
        int cls = blockIdx.x & 7;
        int k = blockIdx.x >> 3;
        int lo = cls * CLS_RANGE, hi = lo + CLS_RANGE;
        for (int e = k * 256 + tid; e < N_EDGES; e += CLS_STRIDE) {
            int d = dst[e];
            if (d >= lo && d < hi) {
                int pos = atomicAdd(&cnt[d], 1);
                if (pos < ROWCAP) srcAp[(size_t)d * ROWCAP + pos] = (unsigned short)src[e];
            }
        }
        return;
    }
    if (blockIdx.x >= CLS_UNITS + TB) {           // ---- pack W2..A4b ----
        int i = 8192 + (blockIdx.x - CLS_UNITS - TB) * 256 + tid;
        if (i >= W_TOTAL) return;
        float v;
        if (i < 16384)      v = W2[i - 8192];
        else if (i < 20480) v = A2a[i - 16384];
        else if (i < 24576) v = A2b[i - 20480];
        else if (i < 32768) v = W3[i - 24576];
        else if (i < 36864) v = A3a[i - 32768];
        else if (i < 40960) v = A3b[i - 36864];
        else if (i < 49152) v = W4[i - 40960];
        else if (i < 53248) v = A4a[i - 49152];
        else                v = A4b[i - 53248];
        wp[i] = f2bf(v);
        return;
    }

    // ---- layer1: h = relu(x @ W1^T + b1) -> Ht (fp16, unscaled) ----
    int wave = ((blockIdx.x - CLS_UNITS) * 256 + tid) >> 6;
    if (wave >= NTILES) return;
    int lane = tid & 63;
    int r16 = lane & 15, quad = lane >> 4;
    int base = wave * 16;

    bf16x8 a[4];
    const float* xr = x + (size_t)(base + r16) * 128 + quad * 8;
#pragma unroll
    for (int kb = 0; kb < 4; kb++) {
        float4 f0 = *(const float4*)(xr + kb * 32);
        float4 f1 = *(const float4*)(xr + kb * 32 + 4);
        bf16x8 v;
        v[0] = (short)f2bf(f0.x); v[1] = (short)f2bf(f0.y);
        v[2] = (short)f2bf(f0.z); v[3] = (short)f2bf(f0.w);
        v[4] = (short)f2bf(f1.x); v[5] = (short)f2bf(f1.y);
        v[6] = (short)f2bf(f1.z); v[7] = (short)f2bf(f1.w);
        a[kb] = v;
    }

#pragma unroll
    for (int jt = 0; jt < 4; jt++) {
        f32x4 acc = {0.f, 0.f, 0.f, 0.f};
        const float* wr = W1 + (size_t)(jt * 16 + r16) * 128 + quad * 8;
#pragma unroll
        for (int kb = 0; kb < 4; kb++) {
            float4 g0 = *(const float4*)(wr + kb * 32);
            float4 g1 = *(const float4*)(wr + kb * 32 + 4);
            bf16x8 b;
            b[0] = (short)f2bf(g0.x); b[1] = (short)f2bf(g0.y);
            b[2] = (short)f2bf(g0.z); b[3] = (short)f2bf(g0.w);
            b[4] = (short)f2bf(g1.x); b[5] = (short)f2bf(g1.y);
            b[6] = (short)f2bf(g1.z); b[7] = (short)f2bf(g1.w);
            acc = __builtin_amdgcn_mfma_f32_16x16x32_bf16(a[kb], b, acc, 0, 0, 0);
        }
        int col = jt * 16 + r16;
        float bias = b1[col];
#pragma unroll
        for (int r = 0; r < 4; r++) {
            int row = base + quad * 4 + r;
            float v = fmaxf(acc[r] + bias, 0.f);
            Ht[(size_t)row * 64 + col] = __float2half(v);
        }
    }
}

// ---------------------------------------------------------------------------
// scale: isq/sdeg from cnt; As = Ht * isq (fp16). 16 threads per row.
__global__ __launch_bounds__(256) void scale_kernel(const int* __restrict__ cnt,
                                                    const __half* __restrict__ Ht,
                                                    __half* __restrict__ As,
                                                    float* __restrict__ isq,
                                                    float* __restrict__ sdeg) {
    int t = blockIdx.x * 256 + threadIdx.x;
    int row = t >> 4, sl = t & 15;
    if (row >= N_NODES) return;
    float dv = fmaxf((float)cnt[row], 1.0f);
    float is = rsqrtf(dv);
    if (sl == 0) {
        isq[row] = is;
        sdeg[row] = sqrtf(dv);
    }
    uint2 rv = *((const uint2*)(Ht + (size_t)row * 64) + sl);   // 4 halves
    float2 fa = h2f2(rv.x), fb = h2f2(rv.y);
    uint2 ov;
    ov.x = f22h2(fa.x * is, fa.y * is);
    ov.y = f22h2(fb.x * is, fb.y * is);
    *((uint2*)(As + (size_t)row * 64) + sl) = ov;
}

// ---------------------------------------------------------------------------
// FUSED conv + dense, one block = 64 rows (4 MFMA tiles, wave-independent).
// conv: padded CSR (row base d*64); 8 feat-lanes x uint4 = 16B gather, one
//   instr serves 8 edges. KEY (R15): slot indices loaded 8-at-a-time as one
//   16B vector -> one srcA latency per 8 edges, then 8 INDEPENDENT gathers
//   in flight (was: per-edge chained scalar srcA load -> gather).
// dense: h A-frags reconstructed as bf16(fp16(hs) * sdeg[row]).
__global__ __launch_bounds__(256) void conv_dense_k(const __half* __restrict__ hs,
                                                    const int* __restrict__ cnt,
                                                    const unsigned short* __restrict__ srcAp,
                                                    const float* __restrict__ isq,
                                                    const float* __restrict__ sdeg,
                                                    const unsigned short* __restrict__ wp,
                                                    const unsigned short* __restrict__ aap,
                                                    const unsigned short* __restrict__ abp,
                                                    __half* __restrict__ outs,
                                                    float* __restrict__ outf,
                                                    int finalLayer) {
    __shared__ unsigned short clds[64][64];   // conv result (bf16), 8 KB
    int tid = threadIdx.x;
    int wv = tid >> 6;
    int lane = tid & 63;
    int t = blockIdx.x * 4 + wv;
    if (t >= NTILES) return;
    int base = t * 16;   // N_NODES % 16 == 0: all rows valid

    // ---- conv phase (no barrier: wave reads only its own clds quarter) ----
    {
        int e8 = lane >> 3, fl = lane & 7;
        const unsigned int* hsp = (const unsigned int*)hs;  // hs row = 32 uints
#pragma unroll
        for (int g = 0; g < 2; g++) {
            int lrow = g * 8 + e8;
            int row = base + lrow;
            int b = row * ROWCAP;
            int cv = min(cnt[row], ROWCAP);
            float acc[8];
#pragma unroll
            for (int k = 0; k < 8; k++) acc[k] = 0.f;
            for (int i = 0; i < cv; i += 8) {
                u16x8 sv = *(const u16x8*)(srcAp + b + i);   // 8 slots, one 16B load
#pragma unroll
                for (int u = 0; u < 8; u++) {
                    int j = i + u;
                    int s = (int)sv[u];                  // poison 0xAAAA < 50000: safe
                    uint4 raw = *(const uint4*)(hsp + (size_t)s * 32 + fl * 4);
                    unsigned int msk = (j < cv) ? 0xFFFFFFFFu : 0u;
                    float2 f0 = h2f2(raw.x & msk);
                    float2 f1 = h2f2(raw.y & msk);
                    float2 f2 = h2f2(raw.z & msk);
                    float2 f3 = h2f2(raw.w & msk);
                    acc[0] += f0.x; acc[1] += f0.y; acc[2] += f1.x; acc[3] += f1.y;
                    acc[4] += f2.x; acc[5] += f2.y; acc[6] += f3.x; acc[7] += f3.y;
                }
            }
            float sc = isq[row];
            u16x8 o;
#pragma unroll
            for (int k = 0; k < 8; k++) o[k] = f2bf(acc[k] * sc);
            *(u16x8*)(&clds[wv * 16 + lrow][fl * 8]) = o;
        }
    }

    // ---- dense phase ----
    int r16 = lane & 15, quad = lane >> 4;
    float rs = sdeg[base + r16];                 // h = hs * sqrt(deg), per A-row
    const unsigned int* hr = (const unsigned int*)(hs + (size_t)(base + r16) * 64) + quad * 4;
    uint4 raw0 = *(const uint4*)(hr);            // feats quad*8 .. +8
    uint4 raw1 = *(const uint4*)(hr + 16);       // feats 32+quad*8 .. +8
    bf16x8 ha0, ha1;
    {
        float2 f;
        f = h2f2(raw0.x); ha0[0] = (short)f2bf(f.x * rs); ha0[1] = (short)f2bf(f.y * rs);
        f = h2f2(raw0.y); ha0[2] = (short)f2bf(f.x * rs); ha0[3] = (short)f2bf(f.y * rs);
        f = h2f2(raw0.z); ha0[4] = (short)f2bf(f.x * rs); ha0[5] = (short)f2bf(f.y * rs);
        f = h2f2(raw0.w); ha0[6] = (short)f2bf(f.x * rs); ha0[7] = (short)f2bf(f.y * rs);
        f = h2f2(raw1.x); ha1[0] = (short)f2bf(f.x * rs); ha1[1] = (short)f2bf(f.y * rs);
        f = h2f2(raw1.y); ha1[2] = (short)f2bf(f.x * rs); ha1[3] = (short)f2bf(f.y * rs);
        f = h2f2(raw1.z); ha1[4] = (short)f2bf(f.x * rs); ha1[5] = (short)f2bf(f.y * rs);
        f = h2f2(raw1.w); ha1[6] = (short)f2bf(f.x * rs); ha1[7] = (short)f2bf(f.y * rs);
    }
    bf16x8 ca0 = *(const bf16x8*)(&clds[wv * 16 + r16][quad * 8]);
    bf16x8 ca1 = *(const bf16x8*)(&clds[wv * 16 + r16][32 + quad * 8]);

    float isq4[4];
    if (!finalLayer) {
#pragma unroll
        for (int r = 0; r < 4; r++) isq4[r] = isq[base + quad * 4 + r];
    }

#pragma unroll
    for (int jt = 0; jt < 4; jt++) {
        const unsigned short* wr = wp + (size_t)(jt * 16 + r16) * 128 + quad * 8;
        const unsigned short* ar = aap + (size_t)(jt * 16 + r16) * 64 + quad * 8;
        const unsigned short* br = abp + (size_t)(jt * 16 + r16) * 64 + quad * 8;
        f32x4 P = {0.f, 0.f, 0.f, 0.f};
        f32x4 Q = {0.f, 0.f, 0.f, 0.f};
        f32x4 R = {0.f, 0.f, 0.f, 0.f};
        P = __builtin_amdgcn_mfma_f32_16x16x32_bf16(ha0, *(const bf16x8*)(wr), P, 0, 0, 0);
        P = __builtin_amdgcn_mfma_f32_16x16x32_bf16(ha1, *(const bf16x8*)(wr + 32), P, 0, 0, 0);
        P = __builtin_amdgcn_mfma_f32_16x16x32_bf16(ca0, *(const bf16x8*)(wr + 64), P, 0, 0, 0);
        P = __builtin_amdgcn_mfma_f32_16x16x32_bf16(ca1, *(const bf16x8*)(wr + 96), P, 0, 0, 0);
        Q = __builtin_amdgcn_mfma_f32_16x16x32_bf16(ha0, *(const bf16x8*)(ar), Q, 0, 0, 0);
        Q = __builtin_amdgcn_mfma_f32_16x16x32_bf16(ha1, *(const bf16x8*)(ar + 32), Q, 0, 0, 0);
        R = __builtin_amdgcn_mfma_f32_16x16x32_bf16(ha0, *(const bf16x8*)(br), R, 0, 0, 0);
        R = __builtin_amdgcn_mfma_f32_16x16x32_bf16(ha1, *(const bf16x8*)(br + 32), R, 0, 0, 0);
        int col = jt * 16 + r16;
#pragma unroll
        for (int r = 0; r < 4; r++) {
            int row = base + quad * 4 + r;
            float v = fmaxf(P[r] + Q[r] * R[r], 0.f);
            if (finalLayer) outf[(size_t)row * 64 + col] = v;
            else            outs[(size_t)row * 64 + col] = __float2half(v * isq4[r]);
        }
    }
}

// ---------------------------------------------------------------------------
extern "C" void kernel_launch(void* const* d_in, const int* in_sizes, int n_in,
                              void* d_out, int out_size, void* d_ws, size_t ws_size,
                              hipStream_t stream) {
    const float* x = (const float*)d_in[0];
    const int* edges = (const int*)d_in[1];
    const float* W1 = (const float*)d_in[2];
    const float* b1 = (const float*)d_in[3];
    const float* W2 = (const float*)d_in[4];
    const float* A2a = (const float*)d_in[5];
    const float* A2b = (const float*)d_in[6];
    const float* W3 = (const float*)d_in[7];
    const float* A3a = (const float*)d_in[8];
    const float* A3b = (const float*)d_in[9];
    const float* W4 = (const float*)d_in[10];
    const float* A4a = (const float*)d_in[11];
    const float* A4b = (const float*)d_in[12];
    float* out = (float*)d_out;

    const int* src = edges;
    const int* dst = edges + N_EDGES;

    char* p = (char*)d_ws;
    auto alloc = [&](size_t bytes) {
        char* r = p;
        p += (bytes + 255) & ~(size_t)255;
        return r;
    };
    int* cnt              = (int*)alloc(N_NODES * 4);
    float* isq            = (float*)alloc(N_NODES * 4);
    float* sdeg           = (float*)alloc(N_NODES * 4);
    unsigned short* srcAp = (unsigned short*)alloc((size_t)N_NODES * ROWCAP * 2);
    unsigned short* wpAll = (unsigned short*)alloc(W_TOTAL * 2);
    __half* Ht            = (__half*)alloc((size_t)N_NODES * 64 * 2);
    __half* As            = (__half*)alloc((size_t)N_NODES * 64 * 2);
    __half* Bs            = (__half*)alloc((size_t)N_NODES * 64 * 2);

    const unsigned short* W2p  = wpAll + 8192;
    const unsigned short* A2ap = wpAll + 16384;
    const unsigned short* A2bp = wpAll + 20480;
    const unsigned short* W3p  = wpAll + 24576;
    const unsigned short* A3ap = wpAll + 32768;
    const unsigned short* A3bp = wpAll + 36864;
    const unsigned short* W4p  = wpAll + 40960;
    const unsigned short* A4ap = wpAll + 49152;
    const unsigned short* A4bp = wpAll + 53248;

    // ---- pass 1: scatter+count (padded CSR) || layer1 || weight pack ----
    hipMemsetAsync(cnt, 0, N_NODES * 4, stream);
    pass1_kernel<<<CLS_UNITS + TB + WB2, 256, 0, stream>>>(
        x, src, dst, W1, b1, W2, A2a, A2b, W3, A3a, A3b, W4, A4a, A4b,
        cnt, srcAp, wpAll, Ht);

    // ---- scale: isq/sdeg + As = Ht*isq ----
    scale_kernel<<<(N_NODES * 16 + 255) / 256, 256, 0, stream>>>(cnt, Ht, As, isq, sdeg);

    // ---- layer 2: As -> Bs ----
    conv_dense_k<<<TB, 256, 0, stream>>>(As, cnt, srcAp, isq, sdeg,
                                         W2p, A2ap, A2bp, Bs, nullptr, 0);
    // ---- layer 3: Bs -> As ----
    conv_dense_k<<<TB, 256, 0, stream>>>(Bs, cnt, srcAp, isq, sdeg,
                                         W3p, A3ap, A3bp, As, nullptr, 0);
    // ---- layer 4: As -> out (fp32) ----
    conv_dense_k<<<TB, 256, 0, stream>>>(As, cnt, srcAp, isq, sdeg,
                                         W4p, A4ap, A4bp, nullptr, out, 1);
}